// Round 2
// baseline (1706.195 us; speedup 1.0000x reference)
//
#include <hip/hip_runtime.h>
#include <math.h>

#define T_OBS 8
#define PRED_LEN 12
#define NSC 512
#define NPED 64
#define NTOT (NSC*NPED)
#define EPS 1e-5

// ---- ws double-region offsets (in doubles) ----
#define O_PWT    0        // pred whh^T [80][320]
#define O_PWIH   25600    // pred wih [320][2]
#define O_PB     26240    // pred bih+bhh [320]
#define O_PLNG   26560
#define O_PLNB   26640
#define O_PWOUT  26720    // [2][80]
#define O_PBOUT  26880    // [2]
#define O_TWIH   26884    // traj wih [128][2]
#define O_TWHHT  27140    // traj whh^T [32][128]
#define O_TB     31236    // traj bih+bhh [128]
#define O_GWIHT  31364    // graph wih^T [32][128]
#define O_GWHHT  35460    // graph whh^T [32][128]
#define O_GB     39556    // graph bih+bhh [128]
#define O_GLNG   39684
#define O_GLNB   39716
#define O_W0     39748    // gat w0 [4][32][16]
#define O_A0S    41796
#define O_A0D    41860
#define O_B0     41924
#define O_W1     41940    // gat w1 [64][32]
#define O_A1S    43988
#define O_A1D    44020
#define O_B1     44052
#define D_TOTAL  44100

__device__ __forceinline__ double dsig(double x){ return 1.0/(1.0+exp(-x)); }

// ---------------- prep: convert all weights to fp64 (and transpose whh's) ----------------
__global__ void k_prep(
    const float* __restrict__ pwhh, const float* __restrict__ pwih,
    const float* __restrict__ pbih, const float* __restrict__ pbhh,
    const float* __restrict__ plng, const float* __restrict__ plnb,
    const float* __restrict__ pwout, const float* __restrict__ pbout,
    const float* __restrict__ twih, const float* __restrict__ twhh,
    const float* __restrict__ tbih, const float* __restrict__ tbhh,
    const float* __restrict__ gwih, const float* __restrict__ gwhh,
    const float* __restrict__ gbih, const float* __restrict__ gbhh,
    const float* __restrict__ glng, const float* __restrict__ glnb,
    const float* __restrict__ w0, const float* __restrict__ a0s,
    const float* __restrict__ a0d, const float* __restrict__ b0,
    const float* __restrict__ w1, const float* __restrict__ a1s,
    const float* __restrict__ a1d, const float* __restrict__ b1,
    double* __restrict__ wsd)
{
  int i = blockIdx.x*256 + threadIdx.x;
  if (i < 25600){ int r = i/80, k = i - r*80; wsd[O_PWT + k*320 + r] = (double)pwhh[i]; }
  if (i < 640)  wsd[O_PWIH + i] = (double)pwih[i];
  if (i < 320)  wsd[O_PB + i] = (double)pbih[i] + (double)pbhh[i];
  if (i < 80){ wsd[O_PLNG + i] = (double)plng[i]; wsd[O_PLNB + i] = (double)plnb[i]; }
  if (i < 160) wsd[O_PWOUT + i] = (double)pwout[i];
  if (i < 2)   wsd[O_PBOUT + i] = (double)pbout[i];
  if (i < 256) wsd[O_TWIH + i] = (double)twih[i];
  if (i < 4096){
    int r = i>>5, k = i&31;
    wsd[O_TWHHT + k*128 + r] = (double)twhh[i];
    wsd[O_GWIHT + k*128 + r] = (double)gwih[i];
    wsd[O_GWHHT + k*128 + r] = (double)gwhh[i];
  }
  if (i < 128){
    wsd[O_TB + i] = (double)tbih[i] + (double)tbhh[i];
    wsd[O_GB + i] = (double)gbih[i] + (double)gbhh[i];
  }
  if (i < 32){
    wsd[O_GLNG + i] = (double)glng[i]; wsd[O_GLNB + i] = (double)glnb[i];
    wsd[O_A1S + i] = (double)a1s[i]; wsd[O_A1D + i] = (double)a1d[i];
    wsd[O_B1 + i] = (double)b1[i];
  }
  if (i < 2048){ wsd[O_W0 + i] = (double)w0[i]; wsd[O_W1 + i] = (double)w1[i]; }
  if (i < 64){ wsd[O_A0S + i] = (double)a0s[i]; wsd[O_A0D + i] = (double)a0d[i]; }
  if (i < 16) wsd[O_B0 + i] = (double)b0[i];
}

// ---------------- K1: traj LSTM (2->32), fp64 compute ----------------
__global__ __launch_bounds__(256) void k_traj(
    const float* __restrict__ obs, const float* __restrict__ h0,
    const float* __restrict__ c0, const double* __restrict__ wsd,
    float* __restrict__ traj_hs)
{
  __shared__ double hdl[32*64];
  const double* wih  = wsd + O_TWIH;
  const double* whhT = wsd + O_TWHHT;
  const double* bd   = wsd + O_TB;
  const int tid = threadIdx.x, lane = tid & 63;
  const int wv = __builtin_amdgcn_readfirstlane(tid >> 6);
  const int ub = wv*8;
  const int ped0 = blockIdx.x*64, ped = ped0 + lane;
  for (int idx = tid; idx < 2048; idx += 256){
    int f = idx>>6, p = idx&63;
    hdl[idx] = (double)h0[(ped0+p)*32 + f];
  }
  double c[8];
  #pragma unroll
  for (int j = 0; j < 8; ++j) c[j] = (double)c0[ped*32 + ub + j];

  for (int t = 0; t < T_OBS; ++t){
    double x0 = (double)obs[((size_t)t*NTOT + ped)*2 + 0];
    double x1 = (double)obs[((size_t)t*NTOT + ped)*2 + 1];
    __syncthreads();
    double acc[32];
    #pragma unroll
    for (int j = 0; j < 8; ++j){
      #pragma unroll
      for (int g = 0; g < 4; ++g){
        int r = g*32 + ub + j;
        acc[j*4+g] = bd[r] + wih[r*2+0]*x0 + wih[r*2+1]*x1;
      }
    }
    for (int k = 0; k < 32; ++k){
      double hk = hdl[k*64 + lane];
      const double* wh = whhT + k*128;
      #pragma unroll
      for (int j = 0; j < 8; ++j){
        #pragma unroll
        for (int g = 0; g < 4; ++g) acc[j*4+g] += wh[g*32 + ub + j]*hk;
      }
    }
    double hn[8];
    #pragma unroll
    for (int j = 0; j < 8; ++j){
      double ig = dsig(acc[j*4+0]);
      double fg = dsig(acc[j*4+1]);
      double gg = tanh(acc[j*4+2]);
      double og = dsig(acc[j*4+3]);
      c[j] = fg*c[j] + ig*gg;
      hn[j] = og*tanh(c[j]);
    }
    __syncthreads();
    #pragma unroll
    for (int j = 0; j < 8; ++j){
      hdl[(ub+j)*64 + lane] = hn[j];
      traj_hs[((size_t)t*NTOT + ped)*32 + ub + j] = (float)hn[j];
    }
  }
}

// ---------------- K2: GAT encoder (fp64 compute, fp32 LDS x / probs) ----------------
__global__ __launch_bounds__(256) void k_gat(
    const float* __restrict__ ths, const double* __restrict__ wsd,
    float* __restrict__ gout)
{
  __shared__ float xA[64*65];
  __shared__ double hpB[64*68];
  __shared__ double as0[256], ad0[256];
  __shared__ double as1[64], ad1[64], Ziv[64], mn[64], rs[64];

  const double* w0  = wsd + O_W0;
  const double* a0s = wsd + O_A0S;
  const double* a0d = wsd + O_A0D;
  const double* b0  = wsd + O_B0;
  const double* w1  = wsd + O_W1;
  const double* a1s = wsd + O_A1S;
  const double* a1d = wsd + O_A1D;
  const double* b1  = wsd + O_B1;

  const int tid = threadIdx.x;
  const int sb = blockIdx.x >> 3, tb = blockIdx.x & 7;
  const int n = tid & 63;
  const int q = __builtin_amdgcn_readfirstlane(tid >> 6);

  const float* xin = ths + ((size_t)tb*NTOT + sb*64)*32;
  for (int idx = tid; idx < 2048; idx += 256)
    xA[(idx>>5)*65 + (idx&31)] = xin[idx];
  __syncthreads();
  if (tid < 32){
    double s1 = 0, s2 = 0;
    for (int p = 0; p < 64; ++p){ double v = xA[p*65+tid]; s1 += v; s2 += v*v; }
    double mu = s1/64.0, va = s2/64.0 - mu*mu;
    mn[tid] = mu; rs[tid] = 1.0/sqrt(va + EPS);
  }
  __syncthreads();
  for (int idx = tid; idx < 2048; idx += 256){
    int p = idx>>5, f = idx&31;
    xA[p*65+f] = (float)(((double)xA[p*65+f] - mn[f])*rs[f]);
  }
  __syncthreads();
  { // hp0 + attn dots
    double acc[16];
    #pragma unroll
    for (int o = 0; o < 16; ++o) acc[o] = 0;
    for (int f = 0; f < 32; ++f){
      double xv = (double)xA[n*65+f];
      const double* wr = w0 + (q*32+f)*16;
      #pragma unroll
      for (int o = 0; o < 16; ++o) acc[o] += xv*wr[o];
    }
    double sa = 0, sd = 0;
    #pragma unroll
    for (int o = 0; o < 16; ++o){
      sa += acc[o]*a0s[q*16+o];
      sd += acc[o]*a0d[q*16+o];
      hpB[n*68 + q*16 + o] = acc[o];
    }
    as0[q*64+n] = sa; ad0[q*64+n] = sd;
  }
  __syncthreads();
  { // attn L0 softmax + aggregate + bias + ELU
    double arow = as0[q*64+n];
    double mx = -1e300;
    for (int m2 = 0; m2 < 64; ++m2){
      double e = arow + ad0[q*64+m2];
      double lr = e > 0 ? e : 0.2*e;
      mx = fmax(mx, lr);
    }
    double num[16];
    #pragma unroll
    for (int o = 0; o < 16; ++o) num[o] = 0;
    double Z = 0;
    for (int m2 = 0; m2 < 64; ++m2){
      double e = arow + ad0[q*64+m2];
      double lr = e > 0 ? e : 0.2*e;
      double pv = exp(lr - mx);
      Z += pv;
      const double2* h2 = (const double2*)&hpB[m2*68 + q*16];
      #pragma unroll
      for (int o2 = 0; o2 < 8; ++o2){
        double2 v = h2[o2];
        num[o2*2+0] += pv*v.x; num[o2*2+1] += pv*v.y;
      }
    }
    double iZ = 1.0/Z;
    #pragma unroll
    for (int o = 0; o < 16; ++o){
      double y = num[o]*iZ + b0[o];
      xA[n*65 + q*16 + o] = (float)(y > 0 ? y : expm1(y));
    }
  }
  __syncthreads();
  if (tid < 64){
    double s1 = 0, s2 = 0;
    for (int p = 0; p < 64; ++p){ double v = xA[p*65+tid]; s1 += v; s2 += v*v; }
    double mu = s1/64.0, va = s2/64.0 - mu*mu;
    mn[tid] = mu; rs[tid] = 1.0/sqrt(va + EPS);
  }
  __syncthreads();
  for (int idx = tid; idx < 4096; idx += 256){
    int p = idx>>6, f = idx&63;
    xA[p*65+f] = (float)(((double)xA[p*65+f] - mn[f])*rs[f]);
  }
  __syncthreads();
  { // hp1
    double a8[8];
    #pragma unroll
    for (int j = 0; j < 8; ++j) a8[j] = 0;
    for (int f = 0; f < 64; ++f){
      double xv = (double)xA[n*65+f];
      const double* wr = w1 + f*32 + q*8;
      #pragma unroll
      for (int j = 0; j < 8; ++j) a8[j] += xv*wr[j];
    }
    #pragma unroll
    for (int j = 0; j < 8; ++j) hpB[n*68 + q*8 + j] = a8[j];
  }
  __syncthreads();
  if (tid < 64){
    double sa = 0, sd = 0;
    for (int o = 0; o < 32; ++o){
      double v = hpB[tid*68 + o];
      sa += v*a1s[o]; sd += v*a1d[o];
    }
    as1[tid] = sa; ad1[tid] = sd;
  }
  __syncthreads();
  if (tid < 64){
    double arow = as1[tid];
    double mx = -1e300;
    for (int m2 = 0; m2 < 64; ++m2){
      double e = arow + ad1[m2];
      double lr = e > 0 ? e : 0.2*e;
      mx = fmax(mx, lr);
    }
    double Z = 0;
    for (int m2 = 0; m2 < 64; ++m2){
      double e = arow + ad1[m2];
      double lr = e > 0 ? e : 0.2*e;
      double pv = exp(lr - mx);
      xA[tid*65+m2] = (float)pv;
      Z += pv;
    }
    Ziv[tid] = 1.0/Z;
  }
  __syncthreads();
  { // aggregate L1, write gin as [t][scene][f][ped]
    double a8[8];
    #pragma unroll
    for (int j = 0; j < 8; ++j) a8[j] = 0;
    for (int m2 = 0; m2 < 64; ++m2){
      double av = (double)xA[n*65+m2];
      const double2* h2 = (const double2*)&hpB[m2*68 + q*8];
      double2 v0 = h2[0], v1 = h2[1], v2 = h2[2], v3 = h2[3];
      a8[0] += av*v0.x; a8[1] += av*v0.y; a8[2] += av*v1.x; a8[3] += av*v1.y;
      a8[4] += av*v2.x; a8[5] += av*v2.y; a8[6] += av*v3.x; a8[7] += av*v3.y;
    }
    double iZ = Ziv[n];
    float* go = gout + ((size_t)(tb*NSC + sb)*32)*64;
    #pragma unroll
    for (int j = 0; j < 8; ++j)
      go[(q*8+j)*64 + n] = (float)(a8[j]*iZ + b1[q*8+j]);
  }
}

// ---------------- K3: graph LSTM (32->32) + LN, fp64 ----------------
__global__ __launch_bounds__(256) void k_graph(
    const float* __restrict__ gin, const float* __restrict__ h0,
    const float* __restrict__ c0, const double* __restrict__ wsd,
    float* __restrict__ gh)
{
  __shared__ double hdl[32*64];
  __shared__ double xld[32*64];
  __shared__ double ps[256], pq[256];
  const double* wihT = wsd + O_GWIHT;
  const double* whhT = wsd + O_GWHHT;
  const double* bd   = wsd + O_GB;
  const double* lng  = wsd + O_GLNG;
  const double* lnb  = wsd + O_GLNB;
  const int tid = threadIdx.x, lane = tid & 63;
  const int wv = __builtin_amdgcn_readfirstlane(tid >> 6);
  const int ub = wv*8;
  const int sb = blockIdx.x, ped0 = sb*64, ped = ped0 + lane;
  for (int idx = tid; idx < 2048; idx += 256){
    int f = idx>>6, p = idx&63;
    hdl[idx] = (double)h0[(ped0+p)*32 + f];
  }
  double c[8];
  #pragma unroll
  for (int j = 0; j < 8; ++j) c[j] = (double)c0[ped*32 + ub + j];

  for (int t = 0; t < T_OBS; ++t){
    __syncthreads();
    const float* gb = gin + (size_t)(t*NSC + sb)*2048;
    for (int idx = tid; idx < 2048; idx += 256) xld[idx] = (double)gb[idx];
    __syncthreads();
    double acc[32];
    #pragma unroll
    for (int j = 0; j < 8; ++j){
      #pragma unroll
      for (int g = 0; g < 4; ++g) acc[j*4+g] = bd[g*32 + ub + j];
    }
    for (int k = 0; k < 32; ++k){
      double xk = xld[k*64 + lane];
      double hk = hdl[k*64 + lane];
      const double* wi = wihT + k*128;
      const double* wh = whhT + k*128;
      #pragma unroll
      for (int j = 0; j < 8; ++j){
        #pragma unroll
        for (int g = 0; g < 4; ++g)
          acc[j*4+g] += wi[g*32 + ub + j]*xk + wh[g*32 + ub + j]*hk;
      }
    }
    double hp[8]; double s1 = 0, s2 = 0;
    #pragma unroll
    for (int j = 0; j < 8; ++j){
      double ig = dsig(acc[j*4+0]);
      double fg = dsig(acc[j*4+1]);
      double gg = tanh(acc[j*4+2]);
      double og = dsig(acc[j*4+3]);
      c[j] = fg*c[j] + ig*gg;
      hp[j] = og*tanh(c[j]);
      s1 += hp[j]; s2 += hp[j]*hp[j];
    }
    ps[wv*64+lane] = s1; pq[wv*64+lane] = s2;
    __syncthreads();
    double mu = (ps[lane]+ps[64+lane]+ps[128+lane]+ps[192+lane])/32.0;
    double va = (pq[lane]+pq[64+lane]+pq[128+lane]+pq[192+lane])/32.0 - mu*mu;
    double ri = 1.0/sqrt(va + EPS);
    #pragma unroll
    for (int j = 0; j < 8; ++j){
      int u = ub + j;
      double hn = (hp[j]-mu)*ri*lng[u] + lnb[u];
      hdl[u*64 + lane] = hn;
      if (t == T_OBS-1) gh[ped*32 + u] = (float)hn;
    }
  }
}

// ---------------- K4: pred LSTM (2->80) + LN + head, 12 steps, fp64 ----------------
// 512 threads = 8 waves over 64 peds; wave w -> units w*10..w*10+9
__global__ __launch_bounds__(512) void k_pred(
    const float* __restrict__ traj_hs, const float* __restrict__ gh,
    const float* __restrict__ zn, const float* __restrict__ obs,
    const double* __restrict__ wsd, float* __restrict__ outm)
{
  __shared__ double hd[80*64];
  __shared__ double ps[512], pq[512];
  __shared__ double po[512*2];
  const double* wT   = wsd + O_PWT;
  const double* wih  = wsd + O_PWIH;
  const double* bd   = wsd + O_PB;
  const double* lng  = wsd + O_PLNG;
  const double* lnb  = wsd + O_PLNB;
  const double* wout = wsd + O_PWOUT;
  const double* bout = wsd + O_PBOUT;
  const int tid = threadIdx.x, lane = tid & 63;
  const int wv = __builtin_amdgcn_readfirstlane(tid >> 6);
  const int ub = wv*10;
  const int scene = blockIdx.x, ped0 = scene*64, ped = ped0 + lane;

  for (int idx = tid; idx < 5120; idx += 512){
    int f = idx>>6, p = idx&63;
    float v;
    if (f < 32)      v = traj_hs[((size_t)7*NTOT + ped0 + p)*32 + f];
    else if (f < 64) v = gh[(ped0+p)*32 + (f-32)];
    else             v = zn[scene*16 + (f-64)];
    hd[idx] = (double)v;
  }
  double c[10];
  #pragma unroll
  for (int j = 0; j < 10; ++j) c[j] = 0.0;
  double x0 = (double)obs[((size_t)7*NTOT + ped)*2 + 0];
  double x1 = (double)obs[((size_t)7*NTOT + ped)*2 + 1];

  for (int t = 0; t < PRED_LEN; ++t){
    __syncthreads();
    double acc[40];
    #pragma unroll
    for (int j = 0; j < 10; ++j){
      #pragma unroll
      for (int g = 0; g < 4; ++g){
        int r = g*80 + ub + j;
        acc[j*4+g] = bd[r] + wih[r*2+0]*x0 + wih[r*2+1]*x1;
      }
    }
    for (int k = 0; k < 80; ++k){
      double hk = hd[k*64 + lane];
      const double* wr = wT + k*320 + ub;
      #pragma unroll
      for (int j = 0; j < 10; ++j){
        acc[j*4+0] += wr[j      ]*hk;
        acc[j*4+1] += wr[ 80 + j]*hk;
        acc[j*4+2] += wr[160 + j]*hk;
        acc[j*4+3] += wr[240 + j]*hk;
      }
    }
    double hp[10]; double s1 = 0, s2 = 0;
    #pragma unroll
    for (int j = 0; j < 10; ++j){
      double ig = dsig(acc[j*4+0]);
      double fg = dsig(acc[j*4+1]);
      double gg = tanh(acc[j*4+2]);
      double og = dsig(acc[j*4+3]);
      c[j] = fg*c[j] + ig*gg;
      hp[j] = og*tanh(c[j]);
      s1 += hp[j]; s2 += hp[j]*hp[j];
    }
    ps[wv*64+lane] = s1; pq[wv*64+lane] = s2;
    __syncthreads();
    double sa = 0, sq = 0;
    #pragma unroll
    for (int w = 0; w < 8; ++w){ sa += ps[w*64+lane]; sq += pq[w*64+lane]; }
    double mu = sa/80.0;
    double va = sq/80.0 - mu*mu;
    double ri = 1.0/sqrt(va + EPS);
    double p0 = 0, p1 = 0;
    #pragma unroll
    for (int j = 0; j < 10; ++j){
      int u = ub + j;
      double hn = (hp[j]-mu)*ri*lng[u] + lnb[u];
      hd[u*64 + lane] = hn;
      p0 += hn*wout[u];
      p1 += hn*wout[80+u];
    }
    po[(wv*64+lane)*2+0] = p0; po[(wv*64+lane)*2+1] = p1;
    __syncthreads();
    double o0 = bout[0], o1 = bout[1];
    #pragma unroll
    for (int w = 0; w < 8; ++w){ o0 += po[(w*64+lane)*2+0]; o1 += po[(w*64+lane)*2+1]; }
    x0 = o0; x1 = o1;
    if (wv == 0){
      outm[((size_t)t*NTOT + ped)*2 + 0] = (float)x0;
      outm[((size_t)t*NTOT + ped)*2 + 1] = (float)x1;
    }
  }
}

// ---------------- K5: constant log_std / std outputs ----------------
__global__ void k_fill(const float* __restrict__ als, float* __restrict__ out) {
  const int M = PRED_LEN*NTOT*2;
  float l0 = als[0], l1 = als[1];
  float e0 = (float)exp((double)l0), e1 = (float)exp((double)l1);
  for (int i = blockIdx.x*256 + threadIdx.x; i < M; i += gridDim.x*256) {
    float lv = (i & 1) ? l1 : l0;
    float ev = (i & 1) ? e1 : e0;
    out[M + i]   = lv;
    out[2*M + i] = ev;
  }
}

extern "C" void kernel_launch(void* const* d_in, const int* in_sizes, int n_in,
                              void* d_out, int out_size, void* d_ws, size_t ws_size,
                              hipStream_t stream)
{
  const float* obs   = (const float*)d_in[0];
  const float* zn    = (const float*)d_in[2];
  const float* th0   = (const float*)d_in[3];
  const float* tc0   = (const float*)d_in[4];
  const float* gh0   = (const float*)d_in[5];
  const float* gc0   = (const float*)d_in[6];
  const float* gw0   = (const float*)d_in[7];
  const float* gas0  = (const float*)d_in[8];
  const float* gad0  = (const float*)d_in[9];
  const float* gb0   = (const float*)d_in[10];
  const float* gw1   = (const float*)d_in[11];
  const float* gas1  = (const float*)d_in[12];
  const float* gad1  = (const float*)d_in[13];
  const float* gb1   = (const float*)d_in[14];
  const float* twih  = (const float*)d_in[15];
  const float* twhh  = (const float*)d_in[16];
  const float* tbih  = (const float*)d_in[17];
  const float* tbhh  = (const float*)d_in[18];
  const float* gwih  = (const float*)d_in[19];
  const float* gwhh  = (const float*)d_in[20];
  const float* gbih  = (const float*)d_in[21];
  const float* gbhh  = (const float*)d_in[22];
  const float* glng  = (const float*)d_in[23];
  const float* glnb  = (const float*)d_in[24];
  const float* pwih  = (const float*)d_in[25];
  const float* pwhh  = (const float*)d_in[26];
  const float* pbih  = (const float*)d_in[27];
  const float* pbhh  = (const float*)d_in[28];
  const float* plng  = (const float*)d_in[29];
  const float* plnb  = (const float*)d_in[30];
  const float* poww  = (const float*)d_in[31];
  const float* pob   = (const float*)d_in[32];
  const float* als   = (const float*)d_in[33];

  float* out = (float*)d_out;
  double* wsd = (double*)d_ws;
  float* traj_hs = (float*)(wsd + D_TOTAL);         // [8][NTOT][32]
  float* gin     = traj_hs + (size_t)8*NTOT*32;     // [8][NSC][32][64]
  float* gh      = gin + (size_t)8*NTOT*32;         // [NTOT][32]

  k_prep<<<dim3(104), dim3(256), 0, stream>>>(
      pwhh, pwih, pbih, pbhh, plng, plnb, poww, pob,
      twih, twhh, tbih, tbhh, gwih, gwhh, gbih, gbhh, glng, glnb,
      gw0, gas0, gad0, gb0, gw1, gas1, gad1, gb1, wsd);
  k_traj<<<dim3(512), dim3(256), 0, stream>>>(obs, th0, tc0, wsd, traj_hs);
  k_gat<<<dim3(4096), dim3(256), 0, stream>>>(traj_hs, wsd, gin);
  k_graph<<<dim3(512), dim3(256), 0, stream>>>(gin, gh0, gc0, wsd, gh);
  k_pred<<<dim3(512), dim3(512), 0, stream>>>(traj_hs, gh, zn, obs, wsd, out);
  k_fill<<<dim3(1024), dim3(256), 0, stream>>>(als, out);
}